// Round 1
// baseline (171.748 us; speedup 1.0000x reference)
//
#include <hip/hip_runtime.h>

// Problem constants
#define BB     32
#define HW_    1600
#define AA     5
#define NN     128
#define CC     80
#define WOUT_  40
#define PRED_PER_B (HW_ * AA)   // 8000

// Output layout (flat float32 concatenation, in reference return order)
#define OFF_BOXES   0
#define SZ_BOXES    (BB * HW_ * AA * 4)          // 1,024,000
#define OFF_IOUS    (OFF_BOXES + SZ_BOXES)       // 1,024,000
#define SZ_IOUS     (BB * HW_ * AA)              //   256,000
#define OFF_CLASSES (OFF_IOUS + SZ_IOUS)         // 1,280,000
#define SZ_CLASSES  (BB * HW_ * AA * CC)         // 20,480,000
#define OFF_BMASK   (OFF_CLASSES + SZ_CLASSES)   // 21,760,000
#define SZ_BMASK    (BB * HW_ * AA)
#define OFF_IMASK   (OFF_BMASK + SZ_BMASK)       // 22,016,000
#define SZ_IMASK    (BB * HW_ * AA)
#define OFF_CMASK   (OFF_IMASK + SZ_IMASK)       // 22,272,000
#define SZ_CMASK    (BB * HW_ * AA)

// ---------------------------------------------------------------------------
// Pass A: one thread per (b, hw, a) prediction slot.
//   - writes default values for boxes_t / ious_t / box_mask / class_mask
//   - computes iou_mask = (any gt with IOU>=0.6) ? 0 : -iou_pred
// Division-free threshold test: iou >= 0.6  <=>  inter >= 0.375*(barea+garea)
// (0.375 = 0.6/1.6 exactly representable).
// ---------------------------------------------------------------------------
__global__ __launch_bounds__(320) void yolo_passA(
    const float* __restrict__ bbox_pred, const float* __restrict__ iou_pred,
    const float* __restrict__ gt, const float* __restrict__ anchors,
    float* __restrict__ boxes_t, float* __restrict__ ious_t,
    float* __restrict__ box_mask, float* __restrict__ iou_mask,
    float* __restrict__ class_mask)
{
    __shared__ float s_g[NN][5];  // x1,y1,x2,y2, 0.375*garea

    const int b     = blockIdx.x / 25;   // 25 blocks of 320 threads cover 8000
    const int chunk = blockIdx.x % 25;
    const int tid   = threadIdx.x;

    for (int n = tid; n < NN; n += 320) {
        const float* gp = gt + (size_t)(b * NN + n) * 5;
        float x1 = gp[0], y1 = gp[1], x2 = gp[2], y2 = gp[3];
        s_g[n][0] = x1; s_g[n][1] = y1; s_g[n][2] = x2; s_g[n][3] = y2;
        float ga = (x2 - x1 + 1.0f) * (y2 - y1 + 1.0f);
        s_g[n][4] = 0.375f * ga;
    }
    __syncthreads();

    const int i  = chunk * 320 + tid;          // 0..7999 within batch
    const int hw = i / AA;
    const int a  = i - hw * AA;
    const int gid = b * PRED_PER_B + i;        // flat (b,hw,a)

    const float4 p = *reinterpret_cast<const float4*>(bbox_pred + (size_t)gid * 4);
    const float col = (float)(hw % WOUT_);
    const float row = (float)(hw / WOUT_);
    const float aw = anchors[a * 2 + 0];
    const float ah = anchors[a * 2 + 1];

    // reference-order arithmetic (true divisions)
    const float cxp = (p.x + col) / 40.0f;
    const float cyp = (p.y + row) / 40.0f;
    const float bw  = p.z * aw / 40.0f * 0.5f;
    const float bh  = p.w * ah / 40.0f * 0.5f;
    const float px1 = (cxp - bw) * 1280.0f;
    const float py1 = (cyp - bh) * 1280.0f;
    const float px2 = (cxp + bw) * 1280.0f;
    const float py2 = (cyp + bh) * 1280.0f;
    const float barea = (px2 - px1 + 1.0f) * (py2 - py1 + 1.0f);
    const float thrB  = 0.375f * barea;

    bool found = false;
    #pragma unroll 4
    for (int n = 0; n < NN; ++n) {
        float iw = fminf(px2, s_g[n][2]) - fmaxf(px1, s_g[n][0]) + 1.0f;
        iw = fmaxf(iw, 0.0f);
        float ih = fminf(py2, s_g[n][3]) - fmaxf(py1, s_g[n][1]) + 1.0f;
        ih = fmaxf(ih, 0.0f);
        float inter = iw * ih;
        found |= (inter >= thrB + s_g[n][4]);
    }

    iou_mask[gid]   = found ? 0.0f : -iou_pred[gid];
    ious_t[gid]     = 0.0f;
    box_mask[gid]   = 0.01f;
    class_mask[gid] = 0.0f;
    float4 bt; bt.x = 0.5f; bt.y = 0.5f; bt.z = 1.0f; bt.w = 1.0f;
    *reinterpret_cast<float4*>(boxes_t + (size_t)gid * 4) = bt;
}

// ---------------------------------------------------------------------------
// Pass B: scatter. One block per batch; 128 threads compute per-gt values,
// thread 0 commits serially in n-order (JAX .set last-wins on duplicates).
// ---------------------------------------------------------------------------
__global__ __launch_bounds__(128) void yolo_passB(
    const float* __restrict__ bbox_pred, const float* __restrict__ iou_pred,
    const float* __restrict__ gt, const float* __restrict__ anchors,
    const int* __restrict__ num_boxes,
    float* __restrict__ boxes_t, float* __restrict__ ious_t,
    float* __restrict__ classes, float* __restrict__ box_mask,
    float* __restrict__ iou_mask, float* __restrict__ class_mask)
{
    const int b = blockIdx.x;
    const int n = threadIdx.x;

    __shared__ int   s_valid[NN];
    __shared__ int   s_flat[NN];
    __shared__ int   s_cls[NN];
    __shared__ float s_iou[NN];
    __shared__ float s_tb[NN][4];

    const float* gp = gt + (size_t)(b * NN + n) * 5;
    const float x1 = gp[0], y1 = gp[1], x2 = gp[2], y2 = gp[3], fc = gp[4];

    const float cx  = (x1 + x2) * 0.5f / 32.0f;
    const float cy  = (y1 + y2) * 0.5f / 32.0f;
    const float fcx = floorf(cx), fcy = floorf(cy);
    const int cell  = (int)(fcy * 40.0f + fcx);
    const float tw  = (x2 - x1 + 1.0f) / 32.0f;
    const float th  = (y2 - y1 + 1.0f) / 32.0f;

    const float gx1 = x1 / 32.0f, gy1 = y1 / 32.0f;
    const float gx2 = x2 / 32.0f, gy2 = y2 / 32.0f;
    const float gw = gx2 - gx1 + 1.0f;
    const float gh = gy2 - gy1 + 1.0f;
    const float gwh = gw * gh;

    // anchor argmax (first-wins on ties, like jnp.argmax)
    int a_ind = 0; float bestA = -1.0f;
    for (int a = 0; a < AA; ++a) {
        float aw = anchors[a * 2 + 0], ah = anchors[a * 2 + 1];
        float iwa = fminf(aw, gw), iha = fminf(ah, gh);
        float inta = iwa * iha;
        float aiou = inta / (aw * ah + gwh - inta);
        if (aiou > bestA) { bestA = aiou; a_ind = a; }
    }
    const float aw = anchors[a_ind * 2 + 0];
    const float ah = anchors[a_ind * 2 + 1];

    const bool valid = (n < num_boxes[b]) && (cell >= 0) && (cell < HW_);
    const int flat = (b * HW_ + cell) * AA + a_ind;

    float iou = 0.0f;
    if (valid) {
        const float* pp = bbox_pred + (size_t)flat * 4;
        const float col = (float)(cell % WOUT_);
        const float rw  = (float)(cell / WOUT_);
        const float cxp = (pp[0] + col) / 40.0f;
        const float cyp = (pp[1] + rw) / 40.0f;
        const float bw  = pp[2] * aw / 40.0f * 0.5f;
        const float bh  = pp[3] * ah / 40.0f * 0.5f;
        const float px1 = (cxp - bw) * 1280.0f;
        const float py1 = (cyp - bh) * 1280.0f;
        const float px2 = (cxp + bw) * 1280.0f;
        const float py2 = (cyp + bh) * 1280.0f;
        const float barea = (px2 - px1 + 1.0f) * (py2 - py1 + 1.0f);
        const float garea = (x2 - x1 + 1.0f) * (y2 - y1 + 1.0f);
        float iw = fmaxf(fminf(px2, x2) - fmaxf(px1, x1) + 1.0f, 0.0f);
        float ih = fmaxf(fminf(py2, y2) - fmaxf(py1, y1) + 1.0f, 0.0f);
        float inter = iw * ih;
        iou = inter / (barea + garea - inter);
    }

    s_valid[n] = valid ? 1 : 0;
    s_flat[n]  = flat;
    s_cls[n]   = (int)fc;
    s_iou[n]   = iou;
    s_tb[n][0] = cx - fcx;
    s_tb[n][1] = cy - fcy;
    s_tb[n][2] = tw / aw;
    s_tb[n][3] = th / ah;
    __syncthreads();

    if (n == 0) {
        for (int m = 0; m < NN; ++m) {
            if (!s_valid[m]) continue;
            const int f = s_flat[m];
            iou_mask[f]   = 5.0f * (1.0f - iou_pred[f]);
            ious_t[f]     = s_iou[m];
            box_mask[f]   = 1.0f;
            class_mask[f] = 1.0f;
            boxes_t[(size_t)f * 4 + 0] = s_tb[m][0];
            boxes_t[(size_t)f * 4 + 1] = s_tb[m][1];
            boxes_t[(size_t)f * 4 + 2] = s_tb[m][2];
            boxes_t[(size_t)f * 4 + 3] = s_tb[m][3];
            classes[(size_t)f * CC + s_cls[m]] = 1.0f;
        }
    }
}

extern "C" void kernel_launch(void* const* d_in, const int* in_sizes, int n_in,
                              void* d_out, int out_size, void* d_ws, size_t ws_size,
                              hipStream_t stream) {
    const float* bbox_pred = (const float*)d_in[0];
    const float* iou_pred  = (const float*)d_in[1];
    const float* gt_boxes  = (const float*)d_in[2];
    const float* anchors   = (const float*)d_in[3];
    const int*   num_boxes = (const int*)d_in[4];
    // d_in[5] = size_index (unused; layout is fixed at size_index=0)

    float* out       = (float*)d_out;
    float* boxes_t   = out + OFF_BOXES;
    float* ious_t    = out + OFF_IOUS;
    float* classes   = out + OFF_CLASSES;
    float* box_mask  = out + OFF_BMASK;
    float* iou_mask  = out + OFF_IMASK;
    float* class_mask= out + OFF_CMASK;

    // classes is zeros except a few scattered 1.0s — memset then scatter.
    hipMemsetAsync(classes, 0, (size_t)SZ_CLASSES * sizeof(float), stream);

    yolo_passA<<<BB * 25, 320, 0, stream>>>(
        bbox_pred, iou_pred, gt_boxes, anchors,
        boxes_t, ious_t, box_mask, iou_mask, class_mask);

    yolo_passB<<<BB, NN, 0, stream>>>(
        bbox_pred, iou_pred, gt_boxes, anchors, num_boxes,
        boxes_t, ious_t, classes, box_mask, iou_mask, class_mask);
}

// Round 2
// 136.535 us; speedup vs baseline: 1.2579x; 1.2579x over previous
//
#include <hip/hip_runtime.h>

// Problem constants
#define BB     32
#define HW_    1600
#define AA     5
#define NN     128
#define CC     80
#define WOUT_  40
#define PRED_PER_B (HW_ * AA)   // 8000

// Output layout (flat float32 concatenation, in reference return order)
#define OFF_BOXES   0
#define SZ_BOXES    (BB * HW_ * AA * 4)          // 1,024,000
#define OFF_IOUS    (OFF_BOXES + SZ_BOXES)       // 1,024,000
#define SZ_IOUS     (BB * HW_ * AA)              //   256,000
#define OFF_CLASSES (OFF_IOUS + SZ_IOUS)         // 1,280,000
#define SZ_CLASSES  (BB * HW_ * AA * CC)         // 20,480,000
#define OFF_BMASK   (OFF_CLASSES + SZ_CLASSES)   // 21,760,000
#define SZ_BMASK    (BB * HW_ * AA)
#define OFF_IMASK   (OFF_BMASK + SZ_BMASK)       // 22,016,000
#define SZ_IMASK    (BB * HW_ * AA)
#define OFF_CMASK   (OFF_IMASK + SZ_IMASK)       // 22,272,000
#define SZ_CMASK    (BB * HW_ * AA)

// ---------------------------------------------------------------------------
// Pass A: one thread per (b, hw, a) prediction slot.
//   - zeroes this block's contiguous slice of `classes` (coalesced float4)
//   - writes default values for boxes_t / ious_t / box_mask / class_mask
//   - computes iou_mask = (any gt with IOU>=0.6) ? 0 : -iou_pred
// Division-free threshold test: iou >= 0.6  <=>  inter >= 0.375*(barea+garea)
// (0.375 = 0.6/1.6 exactly representable). Verified round 1 (absmax 2e-3).
// ---------------------------------------------------------------------------
__global__ __launch_bounds__(320) void yolo_passA(
    const float* __restrict__ bbox_pred, const float* __restrict__ iou_pred,
    const float* __restrict__ gt, const float* __restrict__ anchors,
    float* __restrict__ boxes_t, float* __restrict__ ious_t,
    float* __restrict__ classes, float* __restrict__ box_mask,
    float* __restrict__ iou_mask, float* __restrict__ class_mask)
{
    __shared__ float s_g[NN][5];  // x1,y1,x2,y2, 0.375*garea

    const int b     = blockIdx.x / 25;   // 25 blocks of 320 threads cover 8000
    const int chunk = blockIdx.x % 25;
    const int tid   = threadIdx.x;

    // Zero this block's contiguous classes slice: 320 gids * 80 = 25600 floats
    {
        float4* cbase = reinterpret_cast<float4*>(
            classes + (size_t)(b * PRED_PER_B + chunk * 320) * CC);
        float4 z; z.x = 0.f; z.y = 0.f; z.z = 0.f; z.w = 0.f;
        #pragma unroll
        for (int j = 0; j < 20; ++j)
            cbase[j * 320 + tid] = z;
    }

    for (int n = tid; n < NN; n += 320) {
        const float* gp = gt + (size_t)(b * NN + n) * 5;
        float x1 = gp[0], y1 = gp[1], x2 = gp[2], y2 = gp[3];
        s_g[n][0] = x1; s_g[n][1] = y1; s_g[n][2] = x2; s_g[n][3] = y2;
        float ga = (x2 - x1 + 1.0f) * (y2 - y1 + 1.0f);
        s_g[n][4] = 0.375f * ga;
    }
    __syncthreads();

    const int i  = chunk * 320 + tid;          // 0..7999 within batch
    const int hw = i / AA;
    const int a  = i - hw * AA;
    const int gid = b * PRED_PER_B + i;        // flat (b,hw,a)

    const float4 p = *reinterpret_cast<const float4*>(bbox_pred + (size_t)gid * 4);
    const float col = (float)(hw % WOUT_);
    const float row = (float)(hw / WOUT_);
    const float aw = anchors[a * 2 + 0];
    const float ah = anchors[a * 2 + 1];

    // reference-order arithmetic (true divisions)
    const float cxp = (p.x + col) / 40.0f;
    const float cyp = (p.y + row) / 40.0f;
    const float bw  = p.z * aw / 40.0f * 0.5f;
    const float bh  = p.w * ah / 40.0f * 0.5f;
    const float px1 = (cxp - bw) * 1280.0f;
    const float py1 = (cyp - bh) * 1280.0f;
    const float px2 = (cxp + bw) * 1280.0f;
    const float py2 = (cyp + bh) * 1280.0f;
    const float barea = (px2 - px1 + 1.0f) * (py2 - py1 + 1.0f);
    const float thrB  = 0.375f * barea;

    bool found = false;
    #pragma unroll 4
    for (int n = 0; n < NN; ++n) {
        float iw = fminf(px2, s_g[n][2]) - fmaxf(px1, s_g[n][0]) + 1.0f;
        iw = fmaxf(iw, 0.0f);
        float ih = fminf(py2, s_g[n][3]) - fmaxf(py1, s_g[n][1]) + 1.0f;
        ih = fmaxf(ih, 0.0f);
        float inter = iw * ih;
        found |= (inter >= thrB + s_g[n][4]);
    }

    iou_mask[gid]   = found ? 0.0f : -iou_pred[gid];
    ious_t[gid]     = 0.0f;
    box_mask[gid]   = 0.01f;
    class_mask[gid] = 0.0f;
    float4 bt; bt.x = 0.5f; bt.y = 0.5f; bt.z = 1.0f; bt.w = 1.0f;
    *reinterpret_cast<float4*>(boxes_t + (size_t)gid * 4) = bt;
}

// ---------------------------------------------------------------------------
// Pass B: scatter, fully parallel. One block per batch, one thread per gt.
// Order-free outputs (values depend only on target index): iou_mask, box_mask,
// class_mask, classes — all valid threads write (duplicates write identical
// values / distinct addresses). Order-sensitive (last-wins): ious_t, boxes_t —
// only the highest n among duplicates of the same flat index writes.
// ---------------------------------------------------------------------------
__global__ __launch_bounds__(128) void yolo_passB(
    const float* __restrict__ bbox_pred, const float* __restrict__ iou_pred,
    const float* __restrict__ gt, const float* __restrict__ anchors,
    const int* __restrict__ num_boxes,
    float* __restrict__ boxes_t, float* __restrict__ ious_t,
    float* __restrict__ classes, float* __restrict__ box_mask,
    float* __restrict__ iou_mask, float* __restrict__ class_mask)
{
    const int b = blockIdx.x;
    const int n = threadIdx.x;

    __shared__ int s_key[NN];   // flat index if valid, else -1

    const float* gp = gt + (size_t)(b * NN + n) * 5;
    const float x1 = gp[0], y1 = gp[1], x2 = gp[2], y2 = gp[3], fc = gp[4];

    const float cx  = (x1 + x2) * 0.5f / 32.0f;
    const float cy  = (y1 + y2) * 0.5f / 32.0f;
    const float fcx = floorf(cx), fcy = floorf(cy);
    const int cell  = (int)(fcy * 40.0f + fcx);
    const float tw  = (x2 - x1 + 1.0f) / 32.0f;
    const float th  = (y2 - y1 + 1.0f) / 32.0f;

    const float gx1 = x1 / 32.0f, gy1 = y1 / 32.0f;
    const float gx2 = x2 / 32.0f, gy2 = y2 / 32.0f;
    const float gw = gx2 - gx1 + 1.0f;
    const float gh = gy2 - gy1 + 1.0f;
    const float gwh = gw * gh;

    // anchor argmax (first-wins on ties, like jnp.argmax)
    int a_ind = 0; float bestA = -1.0f;
    for (int a = 0; a < AA; ++a) {
        float aw = anchors[a * 2 + 0], ah = anchors[a * 2 + 1];
        float iwa = fminf(aw, gw), iha = fminf(ah, gh);
        float inta = iwa * iha;
        float aiou = inta / (aw * ah + gwh - inta);
        if (aiou > bestA) { bestA = aiou; a_ind = a; }
    }
    const float aw = anchors[a_ind * 2 + 0];
    const float ah = anchors[a_ind * 2 + 1];

    const bool valid = (n < num_boxes[b]) && (cell >= 0) && (cell < HW_);
    const int flat = (b * HW_ + cell) * AA + a_ind;

    s_key[n] = valid ? flat : -1;
    __syncthreads();

    if (!valid) return;

    // Order-free writes (duplicate f -> identical values; classes -> distinct idx)
    iou_mask[flat]   = 5.0f * (1.0f - iou_pred[flat]);
    box_mask[flat]   = 1.0f;
    class_mask[flat] = 1.0f;
    classes[(size_t)flat * CC + (int)fc] = 1.0f;

    // Last-wins winner check for order-sensitive outputs
    bool winner = true;
    for (int m = n + 1; m < NN; ++m)
        if (s_key[m] == flat) { winner = false; break; }
    if (!winner) return;

    // Recompute the scattered IOU exactly as the reference (true divisions)
    const float* pp = bbox_pred + (size_t)flat * 4;
    const float col = (float)(cell % WOUT_);
    const float rw  = (float)(cell / WOUT_);
    const float cxp = (pp[0] + col) / 40.0f;
    const float cyp = (pp[1] + rw) / 40.0f;
    const float bw  = pp[2] * aw / 40.0f * 0.5f;
    const float bh  = pp[3] * ah / 40.0f * 0.5f;
    const float px1 = (cxp - bw) * 1280.0f;
    const float py1 = (cyp - bh) * 1280.0f;
    const float px2 = (cxp + bw) * 1280.0f;
    const float py2 = (cyp + bh) * 1280.0f;
    const float barea = (px2 - px1 + 1.0f) * (py2 - py1 + 1.0f);
    const float garea = (x2 - x1 + 1.0f) * (y2 - y1 + 1.0f);
    float iw = fmaxf(fminf(px2, x2) - fmaxf(px1, x1) + 1.0f, 0.0f);
    float ih = fmaxf(fminf(py2, y2) - fmaxf(py1, y1) + 1.0f, 0.0f);
    float inter = iw * ih;
    ious_t[flat] = inter / (barea + garea - inter);

    boxes_t[(size_t)flat * 4 + 0] = cx - fcx;
    boxes_t[(size_t)flat * 4 + 1] = cy - fcy;
    boxes_t[(size_t)flat * 4 + 2] = tw / aw;
    boxes_t[(size_t)flat * 4 + 3] = th / ah;
}

extern "C" void kernel_launch(void* const* d_in, const int* in_sizes, int n_in,
                              void* d_out, int out_size, void* d_ws, size_t ws_size,
                              hipStream_t stream) {
    const float* bbox_pred = (const float*)d_in[0];
    const float* iou_pred  = (const float*)d_in[1];
    const float* gt_boxes  = (const float*)d_in[2];
    const float* anchors   = (const float*)d_in[3];
    const int*   num_boxes = (const int*)d_in[4];
    // d_in[5] = size_index (unused; layout is fixed at size_index=0)

    float* out       = (float*)d_out;
    float* boxes_t   = out + OFF_BOXES;
    float* ious_t    = out + OFF_IOUS;
    float* classes   = out + OFF_CLASSES;
    float* box_mask  = out + OFF_BMASK;
    float* iou_mask  = out + OFF_IMASK;
    float* class_mask= out + OFF_CMASK;

    yolo_passA<<<BB * 25, 320, 0, stream>>>(
        bbox_pred, iou_pred, gt_boxes, anchors,
        boxes_t, ious_t, classes, box_mask, iou_mask, class_mask);

    yolo_passB<<<BB, NN, 0, stream>>>(
        bbox_pred, iou_pred, gt_boxes, anchors, num_boxes,
        boxes_t, ious_t, classes, box_mask, iou_mask, class_mask);
}

// Round 4
// 128.791 us; speedup vs baseline: 1.3335x; 1.0601x over previous
//
#include <hip/hip_runtime.h>

// Problem constants
#define BB     32
#define HW_    1600
#define AA     5
#define NN     128
#define CC     80
#define WOUT_  40
#define PRED_PER_B (HW_ * AA)   // 8000

// Output layout (flat float32 concatenation, in reference return order)
#define OFF_BOXES   0
#define SZ_BOXES    (BB * HW_ * AA * 4)          // 1,024,000
#define OFF_IOUS    (OFF_BOXES + SZ_BOXES)       // 1,024,000
#define SZ_IOUS     (BB * HW_ * AA)              //   256,000
#define OFF_CLASSES (OFF_IOUS + SZ_IOUS)         // 1,280,000
#define SZ_CLASSES  (BB * HW_ * AA * CC)         // 20,480,000
#define OFF_BMASK   (OFF_CLASSES + SZ_CLASSES)   // 21,760,000
#define OFF_IMASK   (OFF_BMASK + SZ_IOUS)        // 22,016,000
#define OFF_CMASK   (OFF_IMASK + SZ_IOUS)        // 22,272,000

// ---------------------------------------------------------------------------
// Single fused kernel. One thread per (b, hw, a) prediction slot; 320-thread
// blocks, 25 blocks per batch (each block owns a contiguous 320-gid slice).
//
// Phase 1 (pre-barrier):
//   - zero this block's contiguous `classes` slice (coalesced float4)
//   - load gt boxes into LDS (+ 0.375*garea for the division-free 0.6 test)
//   - threads 0..127: per-gt scatter table {key, cls, tboxes} into LDS
// Phase 2 (post-barrier): each thread
//   - computes its pred box (reference op order), noobj any-IOU>=0.6 test
//   - scans the 128 scatter keys: every match writes classes[gid*80+cls]=1
//     (duplicates hit distinct addresses, like the reference); the LAST
//     match (JAX .set last-wins) selects the scattered values
//   - emits exactly one store per output element with the final value
// classes ordering: zero stores (phase 1, any thread of this block) are
// drained by __syncthreads() (vmcnt(0)+barrier) before the 1.0 stores.
// ---------------------------------------------------------------------------
__global__ __launch_bounds__(320) void yolo_fused(
    const float* __restrict__ bbox_pred, const float* __restrict__ iou_pred,
    const float* __restrict__ gt, const float* __restrict__ anchors,
    const int* __restrict__ num_boxes,
    float* __restrict__ boxes_t, float* __restrict__ ious_t,
    float* __restrict__ classes, float* __restrict__ box_mask,
    float* __restrict__ iou_mask, float* __restrict__ class_mask)
{
    __shared__ float s_g[NN][5];    // x1,y1,x2,y2, 0.375*garea
    __shared__ int   s_key[NN];     // batch-local flat (cell*A+a_ind) or -1
    __shared__ int   s_cls[NN];
    __shared__ float s_tb[NN][4];   // tboxes

    const int b     = blockIdx.x / 25;
    const int chunk = blockIdx.x % 25;
    const int tid   = threadIdx.x;

    // --- zero this block's contiguous classes slice: 320 gids * 80 floats ---
    {
        float4* cbase = reinterpret_cast<float4*>(
            classes + (size_t)(b * PRED_PER_B + chunk * 320) * CC);
        float4 z; z.x = 0.f; z.y = 0.f; z.z = 0.f; z.w = 0.f;
        #pragma unroll
        for (int j = 0; j < 20; ++j)
            cbase[j * 320 + tid] = z;
    }

    // --- gt boxes into LDS ---
    if (tid < NN) {
        const float* gp = gt + (size_t)(b * NN + tid) * 5;
        float x1 = gp[0], y1 = gp[1], x2 = gp[2], y2 = gp[3];
        s_g[tid][0] = x1; s_g[tid][1] = y1; s_g[tid][2] = x2; s_g[tid][3] = y2;
        s_g[tid][4] = 0.375f * ((x2 - x1 + 1.0f) * (y2 - y1 + 1.0f));

        // --- per-gt scatter table ---
        const float fc = gp[4];
        const float cx  = (x1 + x2) * 0.5f / 32.0f;
        const float cy  = (y1 + y2) * 0.5f / 32.0f;
        const float fcx = floorf(cx), fcy = floorf(cy);
        const int cell  = (int)(fcy * 40.0f + fcx);
        const float tw  = (x2 - x1 + 1.0f) / 32.0f;
        const float th  = (y2 - y1 + 1.0f) / 32.0f;

        const float gw = (x2 / 32.0f) - (x1 / 32.0f) + 1.0f;
        const float gh = (y2 / 32.0f) - (y1 / 32.0f) + 1.0f;
        const float gwh = gw * gh;

        // anchor argmax (first-wins on ties, like jnp.argmax)
        int a_ind = 0; float bestA = -1.0f;
        for (int a = 0; a < AA; ++a) {
            float aw = anchors[a * 2 + 0], ah = anchors[a * 2 + 1];
            float iwa = fminf(aw, gw), iha = fminf(ah, gh);
            float inta = iwa * iha;
            float aiou = inta / (aw * ah + gwh - inta);
            if (aiou > bestA) { bestA = aiou; a_ind = a; }
        }
        const float aw = anchors[a_ind * 2 + 0];
        const float ah = anchors[a_ind * 2 + 1];

        const bool valid = (tid < num_boxes[b]) && (cell >= 0) && (cell < HW_);
        s_key[tid]   = valid ? (cell * AA + a_ind) : -1;
        s_cls[tid]   = (int)fc;
        s_tb[tid][0] = cx - fcx;
        s_tb[tid][1] = cy - fcy;
        s_tb[tid][2] = tw / aw;
        s_tb[tid][3] = th / ah;
    }
    __syncthreads();

    // --- per-prediction phase ---
    const int i   = chunk * 320 + tid;         // 0..7999 (batch-local flat)
    const int hw  = i / AA;
    const int a   = i - hw * AA;
    const int gid = b * PRED_PER_B + i;

    const float4 p   = *reinterpret_cast<const float4*>(bbox_pred + (size_t)gid * 4);
    const float ioup = iou_pred[gid];
    const float col = (float)(hw % WOUT_);
    const float row = (float)(hw / WOUT_);
    const float aw = anchors[a * 2 + 0];
    const float ah = anchors[a * 2 + 1];

    // reference-order arithmetic (true divisions)
    const float cxp = (p.x + col) / 40.0f;
    const float cyp = (p.y + row) / 40.0f;
    const float bw  = p.z * aw / 40.0f * 0.5f;
    const float bh  = p.w * ah / 40.0f * 0.5f;
    const float px1 = (cxp - bw) * 1280.0f;
    const float py1 = (cyp - bh) * 1280.0f;
    const float px2 = (cxp + bw) * 1280.0f;
    const float py2 = (cyp + bh) * 1280.0f;
    const float barea = (px2 - px1 + 1.0f) * (py2 - py1 + 1.0f);
    const float thrB  = 0.375f * barea;

    // noobj test: any gt with IOU >= 0.6  (inter >= 0.375*(barea+garea))
    bool found = false;
    #pragma unroll 4
    for (int n = 0; n < NN; ++n) {
        float iw = fminf(px2, s_g[n][2]) - fmaxf(px1, s_g[n][0]) + 1.0f;
        iw = fmaxf(iw, 0.0f);
        float ih = fminf(py2, s_g[n][3]) - fmaxf(py1, s_g[n][1]) + 1.0f;
        ih = fmaxf(ih, 0.0f);
        found |= (iw * ih >= thrB + s_g[n][4]);
    }

    // scatter-match scan: every match sets its class; last match wins values
    int win = -1;
    for (int m = 0; m < NN; ++m) {
        if (s_key[m] == i) {
            classes[(size_t)gid * CC + s_cls[m]] = 1.0f;  // post-barrier: safe
            win = m;
        }
    }
    const bool sc = (win >= 0);

    float iou_w = 0.0f;
    float4 bt;
    if (sc) {
        // scattered IOU: pred box (above) vs winner gt box, reference op order
        const float x1 = s_g[win][0], y1 = s_g[win][1];
        const float x2 = s_g[win][2], y2 = s_g[win][3];
        const float garea = (x2 - x1 + 1.0f) * (y2 - y1 + 1.0f);
        float iw = fmaxf(fminf(px2, x2) - fmaxf(px1, x1) + 1.0f, 0.0f);
        float ih = fmaxf(fminf(py2, y2) - fmaxf(py1, y1) + 1.0f, 0.0f);
        float inter = iw * ih;
        iou_w = inter / (barea + garea - inter);
        bt.x = s_tb[win][0]; bt.y = s_tb[win][1];
        bt.z = s_tb[win][2]; bt.w = s_tb[win][3];
    } else {
        bt.x = 0.5f; bt.y = 0.5f; bt.z = 1.0f; bt.w = 1.0f;
    }

    iou_mask[gid]   = sc ? 5.0f * (1.0f - ioup) : (found ? 0.0f : -ioup);
    ious_t[gid]     = iou_w;
    box_mask[gid]   = sc ? 1.0f : 0.01f;
    class_mask[gid] = sc ? 1.0f : 0.0f;
    *reinterpret_cast<float4*>(boxes_t + (size_t)gid * 4) = bt;
}

extern "C" void kernel_launch(void* const* d_in, const int* in_sizes, int n_in,
                              void* d_out, int out_size, void* d_ws, size_t ws_size,
                              hipStream_t stream) {
    const float* bbox_pred = (const float*)d_in[0];
    const float* iou_pred  = (const float*)d_in[1];
    const float* gt_boxes  = (const float*)d_in[2];
    const float* anchors   = (const float*)d_in[3];
    const int*   num_boxes = (const int*)d_in[4];
    // d_in[5] = size_index (unused; layout is fixed at size_index=0)

    float* out = (float*)d_out;
    yolo_fused<<<BB * 25, 320, 0, stream>>>(
        bbox_pred, iou_pred, gt_boxes, anchors, num_boxes,
        out + OFF_BOXES, out + OFF_IOUS, out + OFF_CLASSES,
        out + OFF_BMASK, out + OFF_IMASK, out + OFF_CMASK);
}